// Round 15
// baseline (440.123 us; speedup 1.0000x reference)
//
#include <hip/hip_runtime.h>
#include <cstdint>
#include <cstddef>

typedef unsigned short u16;
typedef __attribute__((ext_vector_type(8))) short s16x8;
typedef __attribute__((ext_vector_type(4))) float f32x4;

#define NQ   8192
#define TT   512
#define STOK 32

__device__ __forceinline__ float b2f(u16 u) {
    return __uint_as_float(((uint32_t)u) << 16);
}
__device__ __forceinline__ u16 f2b(float f) {
    uint32_t x = __float_as_uint(f);
    uint32_t r = (x + 0x7FFFu + ((x >> 16) & 1u)) >> 16;
    return (u16)r;
}
__device__ __forceinline__ float silu_f(float x) { return x / (1.f + expf(-x)); }

__global__ __launch_bounds__(256) void const_kernel(float v, float* __restrict__ out) {
    int i = blockIdx.x * 256 + threadIdx.x;
    if (i < NQ) out[i] = v;
}

// ---------------------------------------------------------------------------
// features (verified): FIN fp32 [NQ,160] (cols 152..159 = 0), IDX
// ---------------------------------------------------------------------------
__global__ __launch_bounds__(256) void feat32_kernel(
    const float* __restrict__ xy, const float* __restrict__ t_q,
    const int* __restrict__ c, const float* __restrict__ st,
    const float* __restrict__ B, const float* __restrict__ tw,
    const float* __restrict__ tb, const float* __restrict__ ce,
    float* __restrict__ FIN, int* __restrict__ IDX) {
    int n = blockIdx.x, t = threadIdx.x;
    float tq = t_q[n];
    int lo = 0, hi = TT;
    while (lo < hi) {
        int mid = (lo + hi) >> 1;
        if (st[mid] <= tq) lo = mid + 1; else hi = mid;
    }
    int idx = lo - 1;
    if (idx < 0) idx = 0;
    float dt = tq - st[idx];
    if (dt < 0.f) dt = 0.f;
    if (t == 0) IDX[n] = idx;
    float x = xy[2 * n], y = xy[2 * n + 1];
    size_t base = (size_t)n * 160;
    if (t < 64) { float p = x * B[t] + y * B[64 + t]; FIN[base + t] = cosf(p); }
    else if (t < 128) { int j = t - 64; float p = x * B[j] + y * B[64 + j]; FIN[base + t] = sinf(p); }
    else if (t < 144) { int j = t - 128; FIN[base + t] = dt * tw[j] + tb[j]; }
    else if (t < 152) { int j = t - 144; FIN[base + t] = ce[c[n] * 8 + j]; }
    else if (t < 160) { FIN[base + t] = 0.f; }
}

// ---------------------------------------------------------------------------
// pad trunk_in_w [256,152] -> [256,160] and split to bf16 hi/lo
// ---------------------------------------------------------------------------
__global__ __launch_bounds__(256) void padsplit_kernel(const float* __restrict__ w,
                                                       u16* __restrict__ WPh,
                                                       u16* __restrict__ WPl) {
    int i = blockIdx.x * 256 + threadIdx.x;
    if (i < 256 * 160) {
        int r = i / 160, k = i % 160;
        float v = (k < 152) ? w[r * 152 + k] : 0.f;
        u16 h = f2b(v);
        WPh[i] = h;
        WPl[i] = f2b(v - b2f(h));
    }
}

// ---------------------------------------------------------------------------
// split 6 trunk weight matrices into one hi/lo pool (bit-identical to the
// per-block split mgemm2 used to do). Flat layout:
// [0,131072) f1w | [..,262144) f2w | [..,327680) aiw(q rows) |
// [..,393216) aow | [..,458752) w1 | [..,524288) w2
// ---------------------------------------------------------------------------
__global__ __launch_bounds__(256) void wsplit_all(
    const float* __restrict__ f1w, const float* __restrict__ f2w,
    const float* __restrict__ aiw, const float* __restrict__ aow,
    const float* __restrict__ w1, const float* __restrict__ w2,
    u16* __restrict__ WH, u16* __restrict__ WL) {
    int i = blockIdx.x * 256 + threadIdx.x;
    if (i >= 524288) return;
    const float* src; int off;
    if (i < 131072)      { src = f1w; off = i; }
    else if (i < 262144) { src = f2w; off = i - 131072; }
    else if (i < 327680) { src = aiw; off = i - 262144; }
    else if (i < 393216) { src = aow; off = i - 327680; }
    else if (i < 458752) { src = w1;  off = i - 393216; }
    else                 { src = w2;  off = i - 458752; }
    float v = src[off];
    u16 h = f2b(v);
    WH[i] = h;
    WL[i] = f2b(v - b2f(h));
}

// ---------------------------------------------------------------------------
// fold token projection into K/V weights; emit bf16 weights directly
// ---------------------------------------------------------------------------
__global__ __launch_bounds__(256) void combine_kv32(
    const float* __restrict__ aiw, const float* __restrict__ aib,
    const float* __restrict__ btw, const float* __restrict__ btb,
    u16* __restrict__ WKVb, float* __restrict__ bkv) {
    int kv = blockIdx.x >> 8, m = blockIdx.x & 255;
    int d = threadIdx.x;
    __shared__ float wrow[256];
    wrow[d] = aiw[(size_t)(kv + 1) * 65536 + (size_t)m * 256 + d];
    __syncthreads();
    float acc = 0.f;
#pragma unroll 8
    for (int o = 0; o < 256; o++) acc += wrow[o] * btw[(size_t)o * 256 + d];
    WKVb[(size_t)kv * 65536 + (size_t)m * 256 + d] = f2b(acc);
    float pb = wrow[d] * btb[d];
#pragma unroll
    for (int mm = 32; mm >= 1; mm >>= 1) pb += __shfl_xor(pb, mm);
    __shared__ float red[4];
    if ((d & 63) == 0) red[d >> 6] = pb;
    __syncthreads();
    if (d == 0)
        bkv[kv * 256 + m] = red[0] + red[1] + red[2] + red[3] + aib[(kv + 1) * 256 + m];
}

// ---------------------------------------------------------------------------
// M_c = tow_c^T @ bpw_c (bilinear fold); emit bf16 directly
// ---------------------------------------------------------------------------
__global__ __launch_bounds__(256) void mcat_kernel(const float* __restrict__ tow,
                                                   const float* __restrict__ bpw,
                                                   u16* __restrict__ MCATb) {
    const int cc = blockIdx.z;
    const int t0 = blockIdx.x * 16, k0 = blockIdx.y * 16;
    const int lt = threadIdx.x & 15, lj = threadIdx.x >> 4;
    const int ot = threadIdx.x & 15, ok = threadIdx.x >> 4;
    __shared__ float As[16][17], Bs[16][17];
    float acc = 0.f;
    for (int j0 = 0; j0 < 256; j0 += 16) {
        As[lj][lt] = tow[((size_t)cc * 256 + j0 + lj) * 256 + t0 + lt];
        Bs[lj][lt] = bpw[((size_t)cc * 256 + j0 + lj) * 256 + k0 + lt];
        __syncthreads();
#pragma unroll
        for (int jj = 0; jj < 16; jj++) acc += As[jj][ot] * Bs[jj][ok];
        __syncthreads();
    }
    MCATb[((size_t)cc * 256 + t0 + ot) * 256 + k0 + ok] = f2b(acc);
}

__global__ __launch_bounds__(256) void uvs_kernel(
    const float* __restrict__ tow, const float* __restrict__ tob,
    const float* __restrict__ bpw, const float* __restrict__ bpb,
    float* __restrict__ U, float* __restrict__ V, float* __restrict__ S) {
    const int cc = blockIdx.x, t = threadIdx.x;
    float v = 0.f, u = 0.f;
    for (int r = 0; r < 256; r++) {
        v += tow[((size_t)cc * 256 + r) * 256 + t] * bpb[cc * 256 + r];
        u += bpw[((size_t)cc * 256 + r) * 256 + t] * tob[cc * 256 + r];
    }
    V[cc * 256 + t] = v;
    U[cc * 256 + t] = u;
    float sp = tob[cc * 256 + t] * bpb[cc * 256 + t];
#pragma unroll
    for (int m = 32; m >= 1; m >>= 1) sp += __shfl_xor(sp, m);
    __shared__ float red[4];
    if ((t & 63) == 0) red[t >> 6] = sp;
    __syncthreads();
    if (t == 0) S[cc] = red[0] + red[1] + red[2] + red[3];
}

// ---------------------------------------------------------------------------
// per-row LN stats: S[2r]=mean, S[2r+1]=rstd. 4 rows/block.
// ---------------------------------------------------------------------------
__global__ __launch_bounds__(256) void stats_kernel(const float* __restrict__ X,
                                                    float* __restrict__ S) {
    int row = blockIdx.x * 4 + (threadIdx.x >> 6);
    int lane = threadIdx.x & 63;
    float4 v = *(const float4*)&X[(size_t)row * 256 + lane * 4];
    float s = v.x + v.y + v.z + v.w;
    float s2 = v.x * v.x + v.y * v.y + v.z * v.z + v.w * v.w;
#pragma unroll
    for (int m = 32; m >= 1; m >>= 1) {
        s += __shfl_xor(s, m);
        s2 += __shfl_xor(s2, m);
    }
    if (lane == 0) {
        float mean = s * (1.f / 256.f);
        float var = s2 * (1.f / 256.f) - mean * mean;
        S[2 * row] = mean;
        S[2 * row + 1] = rsqrtf(var + 1e-5f);
    }
}

// ---------------------------------------------------------------------------
// counting-sort of queries by IDX (512 buckets) -> perm (L2-locality order)
// ---------------------------------------------------------------------------
__global__ __launch_bounds__(256) void zcnt_kernel(int* __restrict__ cnt) {
    int i = blockIdx.x * 256 + threadIdx.x;
    if (i < TT) cnt[i] = 0;
}
__global__ __launch_bounds__(256) void hist_kernel(const int* __restrict__ IDX,
                                                   int* __restrict__ cnt) {
    int n = blockIdx.x * 256 + threadIdx.x;
    if (n < NQ) atomicAdd(&cnt[IDX[n]], 1);
}
__global__ __launch_bounds__(512) void scan_kernel(const int* __restrict__ cnt,
                                                   int* __restrict__ base,
                                                   int* __restrict__ cur) {
    __shared__ int s[TT];
    int t = threadIdx.x;
    int v = cnt[t];
    s[t] = v;
    __syncthreads();
    for (int off = 1; off < TT; off <<= 1) {
        int add = (t >= off) ? s[t - off] : 0;
        __syncthreads();
        s[t] += add;
        __syncthreads();
    }
    base[t] = s[t] - v;
    cur[t] = s[t] - v;
}
__global__ __launch_bounds__(256) void scat_kernel(const int* __restrict__ IDX,
                                                   int* __restrict__ cur,
                                                   int* __restrict__ perm) {
    int n = blockIdx.x * 256 + threadIdx.x;
    if (n < NQ) {
        int pos = atomicAdd(&cur[IDX[n]], 1);
        perm[pos] = n;
    }
}

// ---------------------------------------------------------------------------
// mgemm_b: MFMA bf16 GEMM, A fp32 (converted on the fly), W pre-converted
// bf16 (direct uint4 load). K=256. ST16: store bf16. SEL: component select.
// ---------------------------------------------------------------------------
template <int ST16, int SEL>
__global__ __launch_bounds__(256) void mgemm_b(
    const float* __restrict__ A, const u16* __restrict__ Wb,
    const float* __restrict__ bias, const int* __restrict__ csel,
    void* __restrict__ Cv) {
    __shared__ u16 As[64 * 40];
    __shared__ u16 Ws[64 * 40];
    const int t = threadIdx.x;
    const size_t rb = (size_t)blockIdx.x * 64;
    const size_t cb = (size_t)blockIdx.y * 64;
    const int wave = t >> 6, lane = t & 63;
    const int m16 = lane & 15, quad = lane >> 4;
    const int sr = t >> 2, sk = (t & 3) * 8;
    const float* Ap = A + (rb + sr) * 256 + sk;
    const u16* Wp = Wb + (cb + sr) * 256 + sk;

    f32x4 acc[4] = {};
    for (int k0 = 0; k0 < 256; k0 += 32) {
        float4 a0 = *(const float4*)(Ap + k0);
        float4 a1 = *(const float4*)(Ap + k0 + 4);
        u16 ta[8] = {f2b(a0.x), f2b(a0.y), f2b(a0.z), f2b(a0.w),
                     f2b(a1.x), f2b(a1.y), f2b(a1.z), f2b(a1.w)};
        *(uint4*)&As[sr * 40 + sk] = *(const uint4*)ta;
        *(uint4*)&Ws[sr * 40 + sk] = *(const uint4*)(Wp + k0);
        __syncthreads();
        s16x8 af = *(const s16x8*)&As[(wave * 16 + m16) * 40 + quad * 8];
#pragma unroll
        for (int ct = 0; ct < 4; ct++) {
            s16x8 bf = *(const s16x8*)&Ws[(ct * 16 + m16) * 40 + quad * 8];
            acc[ct] = __builtin_amdgcn_mfma_f32_16x16x32_bf16(af, bf, acc[ct], 0, 0, 0);
        }
        __syncthreads();
    }
#pragma unroll
    for (int ct = 0; ct < 4; ct++) {
        size_t col = cb + ct * 16 + m16;
        float bb = bias ? bias[col] : 0.f;
#pragma unroll
        for (int r = 0; r < 4; r++) {
            size_t row = rb + wave * 16 + quad * 4 + r;
            float x = acc[ct][r] + bb;
            if (SEL) {
                int comp = (int)(col >> 8);
                if (csel[row] == comp)
                    ((float*)Cv)[row * 256 + (col & 255)] = x;
            } else if (ST16) {
                ((u16*)Cv)[row * 256 + col] = f2b(x);
            } else {
                ((float*)Cv)[row * 256 + col] = x;
            }
        }
    }
}

// ---------------------------------------------------------------------------
// mgemm3: split-precision MFMA GEMM, A fp32 split hi/lo on the fly,
// W PRE-SPLIT hi/lo bf16 (direct loads, zero conversion). 3 MFMAs/step.
// LNA: LN A on load. ACT: silu. RES: C += old. K%32==0.
// ---------------------------------------------------------------------------
template <int LNA, int ACT, int RES>
__global__ __launch_bounds__(256) void mgemm3(
    const float* __restrict__ A, int lda, const u16* __restrict__ WH,
    const u16* __restrict__ WL, const float* __restrict__ bias,
    const float* __restrict__ st, const float* __restrict__ g,
    const float* __restrict__ bln, float* __restrict__ C, int K) {
    __shared__ u16 Ah[64 * 40], Al[64 * 40], Wh[64 * 40], Wl[64 * 40];
    const int t = threadIdx.x;
    const size_t rb = (size_t)blockIdx.x * 64;
    const size_t cb = (size_t)blockIdx.y * 64;
    const int wave = t >> 6, lane = t & 63;
    const int m16 = lane & 15, quad = lane >> 4;
    const int sr = t >> 2, sk = (t & 3) * 8;
    f32x4 acc[4] = {};
    for (int k0 = 0; k0 < K; k0 += 32) {
        {
            const float* p = A + (rb + sr) * (size_t)lda + k0 + sk;
            float4 v0 = *(const float4*)p;
            float4 v1 = *(const float4*)(p + 4);
            float va[8] = {v0.x, v0.y, v0.z, v0.w, v1.x, v1.y, v1.z, v1.w};
            if (LNA) {
                float mm = st[2 * (rb + sr)], ss = st[2 * (rb + sr) + 1];
#pragma unroll
                for (int e = 0; e < 8; e++)
                    va[e] = (va[e] - mm) * ss * g[k0 + sk + e] + bln[k0 + sk + e];
            }
            u16 hi[8], lo[8];
#pragma unroll
            for (int e = 0; e < 8; e++) {
                hi[e] = f2b(va[e]);
                lo[e] = f2b(va[e] - b2f(hi[e]));
            }
            *(uint4*)&Ah[sr * 40 + sk] = *(const uint4*)hi;
            *(uint4*)&Al[sr * 40 + sk] = *(const uint4*)lo;
        }
        *(uint4*)&Wh[sr * 40 + sk] = *(const uint4*)(WH + (cb + sr) * (size_t)K + k0 + sk);
        *(uint4*)&Wl[sr * 40 + sk] = *(const uint4*)(WL + (cb + sr) * (size_t)K + k0 + sk);
        __syncthreads();
        s16x8 ah = *(const s16x8*)&Ah[(wave * 16 + m16) * 40 + quad * 8];
        s16x8 al = *(const s16x8*)&Al[(wave * 16 + m16) * 40 + quad * 8];
#pragma unroll
        for (int ct = 0; ct < 4; ct++) {
            s16x8 bh = *(const s16x8*)&Wh[(ct * 16 + m16) * 40 + quad * 8];
            s16x8 bl = *(const s16x8*)&Wl[(ct * 16 + m16) * 40 + quad * 8];
            acc[ct] = __builtin_amdgcn_mfma_f32_16x16x32_bf16(ah, bh, acc[ct], 0, 0, 0);
            acc[ct] = __builtin_amdgcn_mfma_f32_16x16x32_bf16(ah, bl, acc[ct], 0, 0, 0);
            acc[ct] = __builtin_amdgcn_mfma_f32_16x16x32_bf16(al, bh, acc[ct], 0, 0, 0);
        }
        __syncthreads();
    }
#pragma unroll
    for (int ct = 0; ct < 4; ct++) {
        size_t col = cb + ct * 16 + m16;
        float bb = bias ? bias[col] : 0.f;
#pragma unroll
        for (int r = 0; r < 4; r++) {
            size_t row = rb + wave * 16 + quad * 4 + r;
            float x = acc[ct][r] + bb;
            if (ACT) x = silu_f(x);
            if (RES) x += C[row * 256 + col];
            C[row * 256 + col] = x;
        }
    }
}

// ---------------------------------------------------------------------------
// attn3: one block per query, block b -> query perm[b] (sorted by time index
// for L2 locality of the bf16 KV tiles). In-place Qb -> CTX.
// ---------------------------------------------------------------------------
__global__ __launch_bounds__(256) void attn3_kernel(
    float* __restrict__ QC, const u16* __restrict__ KA, const u16* __restrict__ VA,
    const int* __restrict__ idx, const int* __restrict__ perm) {
    __shared__ float qsh[256], scs[4][STOK], attw[4][STOK];
    const int n = perm[blockIdx.x];
    const int t = threadIdx.x;
    qsh[t] = QC[(size_t)n * 256 + t];
    int ii = idx[n];
    ii = ii < 0 ? 0 : (ii > TT - 1 ? TT - 1 : ii);
    const size_t base = (size_t)ii * STOK * 256;
    __syncthreads();
    if (t < 128) {
        int h = t >> 5, s = t & 31;
        float a = 0.f;
#pragma unroll 8
        for (int d = 0; d < 64; d++)
            a += qsh[h * 64 + d] * b2f(KA[base + (size_t)s * 256 + h * 64 + d]);
        scs[h][s] = a * 0.125f;
    }
    __syncthreads();
    if (t < 4) {
        float mx = -1e30f;
        for (int s = 0; s < STOK; s++) mx = fmaxf(mx, scs[t][s]);
        float sum = 0.f;
        for (int s = 0; s < STOK; s++) { float e = expf(scs[t][s] - mx); attw[t][s] = e; sum += e; }
        for (int s = 0; s < STOK; s++) attw[t][s] /= sum;
    }
    __syncthreads();
    {
        int h = t >> 6;
        float a = 0.f;
#pragma unroll 4
        for (int s = 0; s < STOK; s++)
            a += attw[h][s] * b2f(VA[base + (size_t)s * 256 + t]);
        QC[(size_t)n * 256 + t] = a;
    }
}

// ---------------------------------------------------------------------------
// final dot: out[n] = (F·H + F·v_cc + u_cc·C2 + s_cc) * exp(lt)*cs + cb
// ---------------------------------------------------------------------------
__global__ __launch_bounds__(256) void dot_kernel(
    const float* __restrict__ F, const float* __restrict__ H,
    const float* __restrict__ C2, const int* __restrict__ c,
    const float* __restrict__ U, const float* __restrict__ V,
    const float* __restrict__ S, const float* __restrict__ lt,
    const float* __restrict__ cs, const float* __restrict__ cbv,
    float* __restrict__ out) {
    const int n = blockIdx.x * 4 + (threadIdx.x >> 6);
    const int lane = threadIdx.x & 63;
    const int cc = c[n];
    float4 f4 = *(const float4*)&F[(size_t)n * 256 + lane * 4];
    float4 h4 = *(const float4*)&H[(size_t)n * 256 + lane * 4];
    float4 g4 = *(const float4*)&C2[(size_t)n * 256 + lane * 4];
    float4 v4 = *(const float4*)&V[cc * 256 + lane * 4];
    float4 u4 = *(const float4*)&U[cc * 256 + lane * 4];
    float a = f4.x * (h4.x + v4.x) + f4.y * (h4.y + v4.y) +
              f4.z * (h4.z + v4.z) + f4.w * (h4.w + v4.w) +
              u4.x * g4.x + u4.y * g4.y + u4.z * g4.z + u4.w * g4.w;
#pragma unroll
    for (int m = 32; m >= 1; m >>= 1) a += __shfl_xor(a, m);
    if (lane == 0)
        out[n] = (a + S[cc]) * expf(lt[0]) * cs[cc] + cbv[cc];
}

// ---------------------------------------------------------------------------
extern "C" void kernel_launch(void* const* d_in, const int* in_sizes, int n_in,
                              void* d_out, int out_size, void* d_ws, size_t ws_size,
                              hipStream_t stream) {
    float* out = (float*)d_out;
    const dim3 blk(256);

    static const int EXPECT[38] = {
        16384, 8192, 8192, 4194304, 512, 128, 16, 16, 24,
        38912, 256, 512, 512, 131072, 512, 131072, 512,
        65536, 256, 256, 256, 196608, 768, 65536, 256,
        256, 256, 65536, 256, 65536, 256, 196608, 768,
        196608, 768, 1, 3, 3};
    if (n_in != 38) { const_kernel<<<NQ / 256, blk, 0, stream>>>(99.0e6f, out); return; }
    for (int i = 0; i < 38; i++)
        if (in_sizes[i] != EXPECT[i]) {
            const_kernel<<<NQ / 256, blk, 0, stream>>>((100.0f + i) * 1.0e6f, out);
            return;
        }

    const float* xy  = (const float*)d_in[0];
    const float* tq  = (const float*)d_in[1];
    const int*   c   = (const int*)d_in[2];
    const float* hs  = (const float*)d_in[3];
    const float* st  = (const float*)d_in[4];
    const float* Bm  = (const float*)d_in[5];
    const float* tw  = (const float*)d_in[6];
    const float* tbv = (const float*)d_in[7];
    const float* ce  = (const float*)d_in[8];
    const float* tiw = (const float*)d_in[9];
    const float* tib = (const float*)d_in[10];
    const float* lng = (const float*)d_in[11];
    const float* lnb = (const float*)d_in[12];
    const float* f1w = (const float*)d_in[13];
    const float* f1b = (const float*)d_in[14];
    const float* f2w = (const float*)d_in[15];
    const float* f2b_ = (const float*)d_in[16];
    const float* btw = (const float*)d_in[17];
    const float* btb = (const float*)d_in[18];
    const float* bng = (const float*)d_in[19];
    const float* bnb = (const float*)d_in[20];
    const float* aiw = (const float*)d_in[21];
    const float* aib = (const float*)d_in[22];
    const float* aow = (const float*)d_in[23];
    const float* aob = (const float*)d_in[24];
    const float* clg = (const float*)d_in[25];
    const float* clb = (const float*)d_in[26];
    const float* w1  = (const float*)d_in[27];
    const float* b1  = (const float*)d_in[28];
    const float* w2  = (const float*)d_in[29];
    const float* b2  = (const float*)d_in[30];
    const float* tow = (const float*)d_in[31];
    const float* tob = (const float*)d_in[32];
    const float* bpw = (const float*)d_in[33];
    const float* bpb = (const float*)d_in[34];
    const float* lt  = (const float*)d_in[35];
    const float* cs  = (const float*)d_in[36];
    const float* cbv = (const float*)d_in[37];

    char* ws = (char*)d_ws;
    const size_t MB = 1 << 20;
    if (ws_size < 44 * MB) {  // certified >=48MB (round 7); defensive
        const_kernel<<<NQ / 256, blk, 0, stream>>>(8.0e6f, out);
        return;
    }

    u16*   KA   = (u16*)(ws + 0 * MB);
    u16*   VA   = (u16*)(ws + 8 * MB);
    char*  S_A  = ws + 16 * MB;
    char*  S_B  = ws + 24 * MB;
    char*  S_C  = ws + 32 * MB;
    char*  misc = ws + 40 * MB;
    float* FIN  = (float*)S_A;
    float* Qb   = (float*)S_A;
    float* H1b  = (float*)S_A;
    float* H    = (float*)S_A;
    float* F    = (float*)S_B;
    float* H1   = (float*)S_C;
    float* C2   = (float*)S_C;
    float* STT  = (float*)(misc + 0);                 // [NQ,2]  64KB
    int*   IDX  = (int*)(misc + 64 * 1024);           // 32KB
    float* bkv  = (float*)(misc + 96 * 1024);         // 2KB
    float* Ubuf = (float*)(misc + 100 * 1024);
    float* Vbuf = (float*)(misc + 104 * 1024);
    float* Sbuf = (float*)(misc + 108 * 1024);
    int*   CNT  = (int*)(misc + 112 * 1024);
    int*   BASE = (int*)(misc + 116 * 1024);
    int*   CUR  = (int*)(misc + 120 * 1024);
    int*   PERM = (int*)(misc + 124 * 1024);          // 32KB -> 156K
    u16*   WKVb = (u16*)(misc + 160 * 1024);          // [2,256,256] 256KB
    u16*   MCATb= (u16*)(misc + 416 * 1024);          // [768,256] 384KB
    u16*   WPh  = (u16*)(misc + 800 * 1024);          // [256,160] 80KB
    u16*   WPl  = (u16*)(misc + 880 * 1024);          // 80KB
    u16*   WHp  = (u16*)(misc + 960 * 1024);          // 524288 u16 = 1MB
    u16*   WLp  = (u16*)(misc + 1984 * 1024);         // 1MB -> ends ~2.9MB

    // offsets in the split-weight pool (u16 units)
    const size_t OF1 = 0, OF2 = 131072, OAQ = 262144, OAO = 327680,
                 OW1 = 393216, OW2 = 458752;

    const dim3 gQ(NQ / 64, 4);
    const dim3 gT(TT * STOK / 64, 4);
    const dim3 gSEL(NQ / 64, 12);
    const dim3 gS(NQ / 4);

    // ---- input-only precomputation ----
    padsplit_kernel<<<160, blk, 0, stream>>>(tiw, WPh, WPl);
    wsplit_all<<<2048, blk, 0, stream>>>(f1w, f2w, aiw, aow, w1, w2, WHp, WLp);
    combine_kv32<<<512, blk, 0, stream>>>(aiw, aib, btw, btb, WKVb, bkv);
    mcat_kernel<<<dim3(16, 16, 3), blk, 0, stream>>>(tow, bpw, MCATb);
    uvs_kernel<<<3, blk, 0, stream>>>(tow, tob, bpw, bpb, Ubuf, Vbuf, Sbuf);
    feat32_kernel<<<NQ, blk, 0, stream>>>(xy, tq, c, st, Bm, tw, tbv, ce, FIN, IDX);

    // ---- bucket queries by time index (perm ordering) ----
    zcnt_kernel<<<2, blk, 0, stream>>>(CNT);
    hist_kernel<<<NQ / 256, blk, 0, stream>>>(IDX, CNT);
    scan_kernel<<<1, dim3(512), 0, stream>>>(CNT, BASE, CUR);
    scat_kernel<<<NQ / 256, blk, 0, stream>>>(IDX, CUR, PERM);

    // ---- K/V via MFMA bf16 (pre-converted weights), stored bf16 ----
    mgemm_b<1, 0><<<gT, blk, 0, stream>>>(hs, WKVb, bkv, nullptr, KA);
    mgemm_b<1, 0><<<gT, blk, 0, stream>>>(hs, WKVb + 65536, bkv + 256, nullptr, VA);

    // ---- trunk (split-precision MFMA, pre-split weights) ----
    mgemm3<0, 1, 0><<<gQ, blk, 0, stream>>>(FIN, 160, WPh, WPl, tib, nullptr,
                                            nullptr, nullptr, F, 160);
    for (int i = 0; i < 2; i++) {
        stats_kernel<<<gS, blk, 0, stream>>>(F, STT);
        mgemm3<1, 1, 0><<<gQ, blk, 0, stream>>>(F, 256, WHp + OF1 + (size_t)i * 65536,
                                                WLp + OF1 + (size_t)i * 65536,
                                                f1b + i * 256, STT, lng + i * 256,
                                                lnb + i * 256, H1, 256);
        mgemm3<0, 0, 1><<<gQ, blk, 0, stream>>>(H1, 256, WHp + OF2 + (size_t)i * 65536,
                                                WLp + OF2 + (size_t)i * 65536,
                                                f2b_ + i * 256, nullptr, nullptr,
                                                nullptr, F, 256);
    }
    // ---- q projection ----
    stats_kernel<<<gS, blk, 0, stream>>>(F, STT);
    mgemm3<1, 0, 0><<<gQ, blk, 0, stream>>>(F, 256, WHp + OAQ, WLp + OAQ, aib,
                                            STT, bng, bnb, Qb, 256);
    // ---- attention (per-query blocks, perm-ordered) ----
    attn3_kernel<<<NQ, blk, 0, stream>>>(Qb, KA, VA, IDX, PERM);
    // ---- attn_out ----
    mgemm3<0, 0, 0><<<gQ, blk, 0, stream>>>(Qb, 256, WHp + OAO, WLp + OAO, aob,
                                            nullptr, nullptr, nullptr, C2, 256);
    // ---- bc correction block ----
    stats_kernel<<<gS, blk, 0, stream>>>(C2, STT);
    mgemm3<1, 1, 0><<<gQ, blk, 0, stream>>>(C2, 256, WHp + OW1, WLp + OW1, b1,
                                            STT, clg, clb, H1b, 256);
    mgemm3<0, 0, 1><<<gQ, blk, 0, stream>>>(H1b, 256, WHp + OW2, WLp + OW2, b2,
                                            nullptr, nullptr, nullptr, C2, 256);
    // ---- H[n] = M_{c[n]} @ C2[n] via MFMA SEL (pre-converted MCAT) ----
    mgemm_b<0, 1><<<gSEL, blk, 0, stream>>>(C2, MCATb, nullptr, c, H);
    // ---- final dot ----
    dot_kernel<<<NQ / 4, blk, 0, stream>>>(F, H, C2, c, Ubuf, Vbuf, Sbuf, lt, cs, cbv, out);
}

// Round 16
// 413.885 us; speedup vs baseline: 1.0634x; 1.0634x over previous
//
#include <hip/hip_runtime.h>
#include <cstdint>
#include <cstddef>

typedef unsigned short u16;
typedef __attribute__((ext_vector_type(8))) short s16x8;
typedef __attribute__((ext_vector_type(4))) float f32x4;

#define NQ   8192
#define TT   512
#define STOK 32

__device__ __forceinline__ float b2f(u16 u) {
    return __uint_as_float(((uint32_t)u) << 16);
}
__device__ __forceinline__ u16 f2b(float f) {
    uint32_t x = __float_as_uint(f);
    uint32_t r = (x + 0x7FFFu + ((x >> 16) & 1u)) >> 16;
    return (u16)r;
}
__device__ __forceinline__ float silu_f(float x) { return x / (1.f + expf(-x)); }

__global__ __launch_bounds__(256) void const_kernel(float v, float* __restrict__ out) {
    int i = blockIdx.x * 256 + threadIdx.x;
    if (i < NQ) out[i] = v;
}

// ---------------------------------------------------------------------------
// features (verified): FIN fp32 [NQ,160] (cols 152..159 = 0), IDX
// ---------------------------------------------------------------------------
__global__ __launch_bounds__(256) void feat32_kernel(
    const float* __restrict__ xy, const float* __restrict__ t_q,
    const int* __restrict__ c, const float* __restrict__ st,
    const float* __restrict__ B, const float* __restrict__ tw,
    const float* __restrict__ tb, const float* __restrict__ ce,
    float* __restrict__ FIN, int* __restrict__ IDX) {
    int n = blockIdx.x, t = threadIdx.x;
    float tq = t_q[n];
    int lo = 0, hi = TT;
    while (lo < hi) {
        int mid = (lo + hi) >> 1;
        if (st[mid] <= tq) lo = mid + 1; else hi = mid;
    }
    int idx = lo - 1;
    if (idx < 0) idx = 0;
    float dt = tq - st[idx];
    if (dt < 0.f) dt = 0.f;
    if (t == 0) IDX[n] = idx;
    float x = xy[2 * n], y = xy[2 * n + 1];
    size_t base = (size_t)n * 160;
    if (t < 64) { float p = x * B[t] + y * B[64 + t]; FIN[base + t] = cosf(p); }
    else if (t < 128) { int j = t - 64; float p = x * B[j] + y * B[64 + j]; FIN[base + t] = sinf(p); }
    else if (t < 144) { int j = t - 128; FIN[base + t] = dt * tw[j] + tb[j]; }
    else if (t < 152) { int j = t - 144; FIN[base + t] = ce[c[n] * 8 + j]; }
    else if (t < 160) { FIN[base + t] = 0.f; }
}

// ---------------------------------------------------------------------------
// pad trunk_in_w [256,152] -> [256,160] and split to bf16 hi/lo
// ---------------------------------------------------------------------------
__global__ __launch_bounds__(256) void padsplit_kernel(const float* __restrict__ w,
                                                       u16* __restrict__ WPh,
                                                       u16* __restrict__ WPl) {
    int i = blockIdx.x * 256 + threadIdx.x;
    if (i < 256 * 160) {
        int r = i / 160, k = i % 160;
        float v = (k < 152) ? w[r * 152 + k] : 0.f;
        u16 h = f2b(v);
        WPh[i] = h;
        WPl[i] = f2b(v - b2f(h));
    }
}

// ---------------------------------------------------------------------------
// split 6 trunk weight matrices into one hi/lo pool. Flat layout:
// [0,131072) f1w | [..,262144) f2w | [..,327680) aiw(q rows) |
// [..,393216) aow | [..,458752) w1 | [..,524288) w2
// ---------------------------------------------------------------------------
__global__ __launch_bounds__(256) void wsplit_all(
    const float* __restrict__ f1w, const float* __restrict__ f2w,
    const float* __restrict__ aiw, const float* __restrict__ aow,
    const float* __restrict__ w1, const float* __restrict__ w2,
    u16* __restrict__ WH, u16* __restrict__ WL) {
    int i = blockIdx.x * 256 + threadIdx.x;
    if (i >= 524288) return;
    const float* src; int off;
    if (i < 131072)      { src = f1w; off = i; }
    else if (i < 262144) { src = f2w; off = i - 131072; }
    else if (i < 327680) { src = aiw; off = i - 262144; }
    else if (i < 393216) { src = aow; off = i - 327680; }
    else if (i < 458752) { src = w1;  off = i - 393216; }
    else                 { src = w2;  off = i - 458752; }
    float v = src[off];
    u16 h = f2b(v);
    WH[i] = h;
    WL[i] = f2b(v - b2f(h));
}

// ---------------------------------------------------------------------------
// fold token projection into K/V weights; emit bf16 weights directly
// ---------------------------------------------------------------------------
__global__ __launch_bounds__(256) void combine_kv32(
    const float* __restrict__ aiw, const float* __restrict__ aib,
    const float* __restrict__ btw, const float* __restrict__ btb,
    u16* __restrict__ WKVb, float* __restrict__ bkv) {
    int kv = blockIdx.x >> 8, m = blockIdx.x & 255;
    int d = threadIdx.x;
    __shared__ float wrow[256];
    wrow[d] = aiw[(size_t)(kv + 1) * 65536 + (size_t)m * 256 + d];
    __syncthreads();
    float acc = 0.f;
#pragma unroll 8
    for (int o = 0; o < 256; o++) acc += wrow[o] * btw[(size_t)o * 256 + d];
    WKVb[(size_t)kv * 65536 + (size_t)m * 256 + d] = f2b(acc);
    float pb = wrow[d] * btb[d];
#pragma unroll
    for (int mm = 32; mm >= 1; mm >>= 1) pb += __shfl_xor(pb, mm);
    __shared__ float red[4];
    if ((d & 63) == 0) red[d >> 6] = pb;
    __syncthreads();
    if (d == 0)
        bkv[kv * 256 + m] = red[0] + red[1] + red[2] + red[3] + aib[(kv + 1) * 256 + m];
}

// ---------------------------------------------------------------------------
// M_c = tow_c^T @ bpw_c (bilinear fold); emit bf16 directly
// ---------------------------------------------------------------------------
__global__ __launch_bounds__(256) void mcat_kernel(const float* __restrict__ tow,
                                                   const float* __restrict__ bpw,
                                                   u16* __restrict__ MCATb) {
    const int cc = blockIdx.z;
    const int t0 = blockIdx.x * 16, k0 = blockIdx.y * 16;
    const int lt = threadIdx.x & 15, lj = threadIdx.x >> 4;
    const int ot = threadIdx.x & 15, ok = threadIdx.x >> 4;
    __shared__ float As[16][17], Bs[16][17];
    float acc = 0.f;
    for (int j0 = 0; j0 < 256; j0 += 16) {
        As[lj][lt] = tow[((size_t)cc * 256 + j0 + lj) * 256 + t0 + lt];
        Bs[lj][lt] = bpw[((size_t)cc * 256 + j0 + lj) * 256 + k0 + lt];
        __syncthreads();
#pragma unroll
        for (int jj = 0; jj < 16; jj++) acc += As[jj][ot] * Bs[jj][ok];
        __syncthreads();
    }
    MCATb[((size_t)cc * 256 + t0 + ot) * 256 + k0 + ok] = f2b(acc);
}

__global__ __launch_bounds__(256) void uvs_kernel(
    const float* __restrict__ tow, const float* __restrict__ tob,
    const float* __restrict__ bpw, const float* __restrict__ bpb,
    float* __restrict__ U, float* __restrict__ V, float* __restrict__ S) {
    const int cc = blockIdx.x, t = threadIdx.x;
    float v = 0.f, u = 0.f;
    for (int r = 0; r < 256; r++) {
        v += tow[((size_t)cc * 256 + r) * 256 + t] * bpb[cc * 256 + r];
        u += bpw[((size_t)cc * 256 + r) * 256 + t] * tob[cc * 256 + r];
    }
    V[cc * 256 + t] = v;
    U[cc * 256 + t] = u;
    float sp = tob[cc * 256 + t] * bpb[cc * 256 + t];
#pragma unroll
    for (int m = 32; m >= 1; m >>= 1) sp += __shfl_xor(sp, m);
    __shared__ float red[4];
    if ((t & 63) == 0) red[t >> 6] = sp;
    __syncthreads();
    if (t == 0) S[cc] = red[0] + red[1] + red[2] + red[3];
}

// ---------------------------------------------------------------------------
// per-row LN stats: S[2r]=mean, S[2r+1]=rstd. 4 rows/block.
// ---------------------------------------------------------------------------
__global__ __launch_bounds__(256) void stats_kernel(const float* __restrict__ X,
                                                    float* __restrict__ S) {
    int row = blockIdx.x * 4 + (threadIdx.x >> 6);
    int lane = threadIdx.x & 63;
    float4 v = *(const float4*)&X[(size_t)row * 256 + lane * 4];
    float s = v.x + v.y + v.z + v.w;
    float s2 = v.x * v.x + v.y * v.y + v.z * v.z + v.w * v.w;
#pragma unroll
    for (int m = 32; m >= 1; m >>= 1) {
        s += __shfl_xor(s, m);
        s2 += __shfl_xor(s2, m);
    }
    if (lane == 0) {
        float mean = s * (1.f / 256.f);
        float var = s2 * (1.f / 256.f) - mean * mean;
        S[2 * row] = mean;
        S[2 * row + 1] = rsqrtf(var + 1e-5f);
    }
}

// ---------------------------------------------------------------------------
// counting-sort of queries by IDX (512 buckets) -> perm (L2-locality order)
// ---------------------------------------------------------------------------
__global__ __launch_bounds__(256) void zcnt_kernel(int* __restrict__ cnt) {
    int i = blockIdx.x * 256 + threadIdx.x;
    if (i < TT) cnt[i] = 0;
}
__global__ __launch_bounds__(256) void hist_kernel(const int* __restrict__ IDX,
                                                   int* __restrict__ cnt) {
    int n = blockIdx.x * 256 + threadIdx.x;
    if (n < NQ) atomicAdd(&cnt[IDX[n]], 1);
}
__global__ __launch_bounds__(512) void scan_kernel(const int* __restrict__ cnt,
                                                   int* __restrict__ base,
                                                   int* __restrict__ cur) {
    __shared__ int s[TT];
    int t = threadIdx.x;
    int v = cnt[t];
    s[t] = v;
    __syncthreads();
    for (int off = 1; off < TT; off <<= 1) {
        int add = (t >= off) ? s[t - off] : 0;
        __syncthreads();
        s[t] += add;
        __syncthreads();
    }
    base[t] = s[t] - v;
    cur[t] = s[t] - v;
}
__global__ __launch_bounds__(256) void scat_kernel(const int* __restrict__ IDX,
                                                   int* __restrict__ cur,
                                                   int* __restrict__ perm) {
    int n = blockIdx.x * 256 + threadIdx.x;
    if (n < NQ) {
        int pos = atomicAdd(&cur[IDX[n]], 1);
        perm[pos] = n;
    }
}

// ---------------------------------------------------------------------------
// mgemm_b: MFMA bf16 GEMM, A fp32 (converted on the fly), W pre-converted
// bf16 (direct uint4 load). K=256. ST16: store bf16. SEL: component select.
// ---------------------------------------------------------------------------
template <int ST16, int SEL>
__global__ __launch_bounds__(256) void mgemm_b(
    const float* __restrict__ A, const u16* __restrict__ Wb,
    const float* __restrict__ bias, const int* __restrict__ csel,
    void* __restrict__ Cv) {
    __shared__ u16 As[64 * 40];
    __shared__ u16 Ws[64 * 40];
    const int t = threadIdx.x;
    const size_t rb = (size_t)blockIdx.x * 64;
    const size_t cb = (size_t)blockIdx.y * 64;
    const int wave = t >> 6, lane = t & 63;
    const int m16 = lane & 15, quad = lane >> 4;
    const int sr = t >> 2, sk = (t & 3) * 8;
    const float* Ap = A + (rb + sr) * 256 + sk;
    const u16* Wp = Wb + (cb + sr) * 256 + sk;

    f32x4 acc[4] = {};
    for (int k0 = 0; k0 < 256; k0 += 32) {
        float4 a0 = *(const float4*)(Ap + k0);
        float4 a1 = *(const float4*)(Ap + k0 + 4);
        u16 ta[8] = {f2b(a0.x), f2b(a0.y), f2b(a0.z), f2b(a0.w),
                     f2b(a1.x), f2b(a1.y), f2b(a1.z), f2b(a1.w)};
        *(uint4*)&As[sr * 40 + sk] = *(const uint4*)ta;
        *(uint4*)&Ws[sr * 40 + sk] = *(const uint4*)(Wp + k0);
        __syncthreads();
        s16x8 af = *(const s16x8*)&As[(wave * 16 + m16) * 40 + quad * 8];
#pragma unroll
        for (int ct = 0; ct < 4; ct++) {
            s16x8 bf = *(const s16x8*)&Ws[(ct * 16 + m16) * 40 + quad * 8];
            acc[ct] = __builtin_amdgcn_mfma_f32_16x16x32_bf16(af, bf, acc[ct], 0, 0, 0);
        }
        __syncthreads();
    }
#pragma unroll
    for (int ct = 0; ct < 4; ct++) {
        size_t col = cb + ct * 16 + m16;
        float bb = bias ? bias[col] : 0.f;
#pragma unroll
        for (int r = 0; r < 4; r++) {
            size_t row = rb + wave * 16 + quad * 4 + r;
            float x = acc[ct][r] + bb;
            if (SEL) {
                int comp = (int)(col >> 8);
                if (csel[row] == comp)
                    ((float*)Cv)[row * 256 + (col & 255)] = x;
            } else if (ST16) {
                ((u16*)Cv)[row * 256 + col] = f2b(x);
            } else {
                ((float*)Cv)[row * 256 + col] = x;
            }
        }
    }
}

// ---------------------------------------------------------------------------
// mgemm3: split-precision MFMA GEMM, A fp32 split hi/lo on the fly,
// W PRE-SPLIT hi/lo bf16. 3 MFMAs/step. LNA/ACT/RES as before.
// ---------------------------------------------------------------------------
template <int LNA, int ACT, int RES>
__global__ __launch_bounds__(256) void mgemm3(
    const float* __restrict__ A, int lda, const u16* __restrict__ WH,
    const u16* __restrict__ WL, const float* __restrict__ bias,
    const float* __restrict__ st, const float* __restrict__ g,
    const float* __restrict__ bln, float* __restrict__ C, int K) {
    __shared__ u16 Ah[64 * 40], Al[64 * 40], Wh[64 * 40], Wl[64 * 40];
    const int t = threadIdx.x;
    const size_t rb = (size_t)blockIdx.x * 64;
    const size_t cb = (size_t)blockIdx.y * 64;
    const int wave = t >> 6, lane = t & 63;
    const int m16 = lane & 15, quad = lane >> 4;
    const int sr = t >> 2, sk = (t & 3) * 8;
    f32x4 acc[4] = {};
    for (int k0 = 0; k0 < K; k0 += 32) {
        {
            const float* p = A + (rb + sr) * (size_t)lda + k0 + sk;
            float4 v0 = *(const float4*)p;
            float4 v1 = *(const float4*)(p + 4);
            float va[8] = {v0.x, v0.y, v0.z, v0.w, v1.x, v1.y, v1.z, v1.w};
            if (LNA) {
                float mm = st[2 * (rb + sr)], ss = st[2 * (rb + sr) + 1];
#pragma unroll
                for (int e = 0; e < 8; e++)
                    va[e] = (va[e] - mm) * ss * g[k0 + sk + e] + bln[k0 + sk + e];
            }
            u16 hi[8], lo[8];
#pragma unroll
            for (int e = 0; e < 8; e++) {
                hi[e] = f2b(va[e]);
                lo[e] = f2b(va[e] - b2f(hi[e]));
            }
            *(uint4*)&Ah[sr * 40 + sk] = *(const uint4*)hi;
            *(uint4*)&Al[sr * 40 + sk] = *(const uint4*)lo;
        }
        *(uint4*)&Wh[sr * 40 + sk] = *(const uint4*)(WH + (cb + sr) * (size_t)K + k0 + sk);
        *(uint4*)&Wl[sr * 40 + sk] = *(const uint4*)(WL + (cb + sr) * (size_t)K + k0 + sk);
        __syncthreads();
        s16x8 ah = *(const s16x8*)&Ah[(wave * 16 + m16) * 40 + quad * 8];
        s16x8 al = *(const s16x8*)&Al[(wave * 16 + m16) * 40 + quad * 8];
#pragma unroll
        for (int ct = 0; ct < 4; ct++) {
            s16x8 bh = *(const s16x8*)&Wh[(ct * 16 + m16) * 40 + quad * 8];
            s16x8 bl = *(const s16x8*)&Wl[(ct * 16 + m16) * 40 + quad * 8];
            acc[ct] = __builtin_amdgcn_mfma_f32_16x16x32_bf16(ah, bh, acc[ct], 0, 0, 0);
            acc[ct] = __builtin_amdgcn_mfma_f32_16x16x32_bf16(ah, bl, acc[ct], 0, 0, 0);
            acc[ct] = __builtin_amdgcn_mfma_f32_16x16x32_bf16(al, bh, acc[ct], 0, 0, 0);
        }
        __syncthreads();
    }
#pragma unroll
    for (int ct = 0; ct < 4; ct++) {
        size_t col = cb + ct * 16 + m16;
        float bb = bias ? bias[col] : 0.f;
#pragma unroll
        for (int r = 0; r < 4; r++) {
            size_t row = rb + wave * 16 + quad * 4 + r;
            float x = acc[ct][r] + bb;
            if (ACT) x = silu_f(x);
            if (RES) x += C[row * 256 + col];
            C[row * 256 + col] = x;
        }
    }
}

// ---------------------------------------------------------------------------
// attn4: one block per query (perm-ordered). K read vectorized from global
// (8x uint4 per score thread, split accumulators); V staged vectorized into
// LDS (pitch 264 -> conflict-free ctx reads); softmax parallel via shfl.
// In-place Qb -> CTX.
// ---------------------------------------------------------------------------
__global__ __launch_bounds__(256) void attn4_kernel(
    float* __restrict__ QC, const u16* __restrict__ KA, const u16* __restrict__ VA,
    const int* __restrict__ idx, const int* __restrict__ perm) {
    __shared__ u16 vsh[STOK * 264];
    __shared__ float qsh[256], attw[4][STOK];
    const int n = perm[blockIdx.x];
    const int t = threadIdx.x;
    qsh[t] = QC[(size_t)n * 256 + t];
    int ii = idx[n];
    ii = ii < 0 ? 0 : (ii > TT - 1 ? TT - 1 : ii);
    const size_t base = (size_t)ii * STOK * 256;
    // stage V: 32 rows x 256 u16 = 1024 uint4, 4 per thread, coalesced
#pragma unroll
    for (int i = t; i < 1024; i += 256) {
        int s = i >> 5, dq = (i & 31) * 8;
        *(uint4*)&vsh[s * 264 + dq] = *(const uint4*)&VA[base + (size_t)s * 256 + dq];
    }
    __syncthreads();
    if (t < 128) {
        int h = t >> 5, s = t & 31;
        const u16* kp = KA + base + (size_t)s * 256 + h * 64;
        uint4 kv[8];
#pragma unroll
        for (int dq = 0; dq < 8; dq++) kv[dq] = *(const uint4*)(kp + dq * 8);
        float p0 = 0.f, p1 = 0.f;
#pragma unroll
        for (int dq = 0; dq < 8; dq++) {
            const u16* ks = (const u16*)&kv[dq];
            float a0 = 0.f;
#pragma unroll
            for (int j = 0; j < 8; j++) a0 += qsh[h * 64 + dq * 8 + j] * b2f(ks[j]);
            if (dq & 1) p1 += a0; else p0 += a0;
        }
        float sc = (p0 + p1) * 0.125f;
        // parallel softmax across the 32 s-lanes of this head group
        float mx = sc;
#pragma unroll
        for (int m = 16; m >= 1; m >>= 1) mx = fmaxf(mx, __shfl_xor(mx, m));
        float e = expf(sc - mx);
        float sum = e;
#pragma unroll
        for (int m = 16; m >= 1; m >>= 1) sum += __shfl_xor(sum, m);
        attw[h][s] = e / sum;
    }
    __syncthreads();
    {
        int h = t >> 6;
        float a = 0.f;
#pragma unroll 8
        for (int s = 0; s < STOK; s++) a += attw[h][s] * b2f(vsh[s * 264 + t]);
        QC[(size_t)n * 256 + t] = a;
    }
}

// ---------------------------------------------------------------------------
// final dot: out[n] = (F·H + F·v_cc + u_cc·C2 + s_cc) * exp(lt)*cs + cb
// ---------------------------------------------------------------------------
__global__ __launch_bounds__(256) void dot_kernel(
    const float* __restrict__ F, const float* __restrict__ H,
    const float* __restrict__ C2, const int* __restrict__ c,
    const float* __restrict__ U, const float* __restrict__ V,
    const float* __restrict__ S, const float* __restrict__ lt,
    const float* __restrict__ cs, const float* __restrict__ cbv,
    float* __restrict__ out) {
    const int n = blockIdx.x * 4 + (threadIdx.x >> 6);
    const int lane = threadIdx.x & 63;
    const int cc = c[n];
    float4 f4 = *(const float4*)&F[(size_t)n * 256 + lane * 4];
    float4 h4 = *(const float4*)&H[(size_t)n * 256 + lane * 4];
    float4 g4 = *(const float4*)&C2[(size_t)n * 256 + lane * 4];
    float4 v4 = *(const float4*)&V[cc * 256 + lane * 4];
    float4 u4 = *(const float4*)&U[cc * 256 + lane * 4];
    float a = f4.x * (h4.x + v4.x) + f4.y * (h4.y + v4.y) +
              f4.z * (h4.z + v4.z) + f4.w * (h4.w + v4.w) +
              u4.x * g4.x + u4.y * g4.y + u4.z * g4.z + u4.w * g4.w;
#pragma unroll
    for (int m = 32; m >= 1; m >>= 1) a += __shfl_xor(a, m);
    if (lane == 0)
        out[n] = (a + S[cc]) * expf(lt[0]) * cs[cc] + cbv[cc];
}

// ---------------------------------------------------------------------------
extern "C" void kernel_launch(void* const* d_in, const int* in_sizes, int n_in,
                              void* d_out, int out_size, void* d_ws, size_t ws_size,
                              hipStream_t stream) {
    float* out = (float*)d_out;
    const dim3 blk(256);

    static const int EXPECT[38] = {
        16384, 8192, 8192, 4194304, 512, 128, 16, 16, 24,
        38912, 256, 512, 512, 131072, 512, 131072, 512,
        65536, 256, 256, 256, 196608, 768, 65536, 256,
        256, 256, 65536, 256, 65536, 256, 196608, 768,
        196608, 768, 1, 3, 3};
    if (n_in != 38) { const_kernel<<<NQ / 256, blk, 0, stream>>>(99.0e6f, out); return; }
    for (int i = 0; i < 38; i++)
        if (in_sizes[i] != EXPECT[i]) {
            const_kernel<<<NQ / 256, blk, 0, stream>>>((100.0f + i) * 1.0e6f, out);
            return;
        }

    const float* xy  = (const float*)d_in[0];
    const float* tq  = (const float*)d_in[1];
    const int*   c   = (const int*)d_in[2];
    const float* hs  = (const float*)d_in[3];
    const float* st  = (const float*)d_in[4];
    const float* Bm  = (const float*)d_in[5];
    const float* tw  = (const float*)d_in[6];
    const float* tbv = (const float*)d_in[7];
    const float* ce  = (const float*)d_in[8];
    const float* tiw = (const float*)d_in[9];
    const float* tib = (const float*)d_in[10];
    const float* lng = (const float*)d_in[11];
    const float* lnb = (const float*)d_in[12];
    const float* f1w = (const float*)d_in[13];
    const float* f1b = (const float*)d_in[14];
    const float* f2w = (const float*)d_in[15];
    const float* f2b_ = (const float*)d_in[16];
    const float* btw = (const float*)d_in[17];
    const float* btb = (const float*)d_in[18];
    const float* bng = (const float*)d_in[19];
    const float* bnb = (const float*)d_in[20];
    const float* aiw = (const float*)d_in[21];
    const float* aib = (const float*)d_in[22];
    const float* aow = (const float*)d_in[23];
    const float* aob = (const float*)d_in[24];
    const float* clg = (const float*)d_in[25];
    const float* clb = (const float*)d_in[26];
    const float* w1  = (const float*)d_in[27];
    const float* b1  = (const float*)d_in[28];
    const float* w2  = (const float*)d_in[29];
    const float* b2  = (const float*)d_in[30];
    const float* tow = (const float*)d_in[31];
    const float* tob = (const float*)d_in[32];
    const float* bpw = (const float*)d_in[33];
    const float* bpb = (const float*)d_in[34];
    const float* lt  = (const float*)d_in[35];
    const float* cs  = (const float*)d_in[36];
    const float* cbv = (const float*)d_in[37];

    char* ws = (char*)d_ws;
    const size_t MB = 1 << 20;
    if (ws_size < 44 * MB) {  // certified >=48MB (round 7); defensive
        const_kernel<<<NQ / 256, blk, 0, stream>>>(8.0e6f, out);
        return;
    }

    u16*   KA   = (u16*)(ws + 0 * MB);
    u16*   VA   = (u16*)(ws + 8 * MB);
    char*  S_A  = ws + 16 * MB;
    char*  S_B  = ws + 24 * MB;
    char*  S_C  = ws + 32 * MB;
    char*  misc = ws + 40 * MB;
    float* FIN  = (float*)S_A;
    float* Qb   = (float*)S_A;
    float* H1b  = (float*)S_A;
    float* H    = (float*)S_A;
    float* F    = (float*)S_B;
    float* H1   = (float*)S_C;
    float* C2   = (float*)S_C;
    float* STT  = (float*)(misc + 0);                 // [NQ,2]  64KB
    int*   IDX  = (int*)(misc + 64 * 1024);           // 32KB
    float* bkv  = (float*)(misc + 96 * 1024);         // 2KB
    float* Ubuf = (float*)(misc + 100 * 1024);
    float* Vbuf = (float*)(misc + 104 * 1024);
    float* Sbuf = (float*)(misc + 108 * 1024);
    int*   CNT  = (int*)(misc + 112 * 1024);
    int*   BASE = (int*)(misc + 116 * 1024);
    int*   CUR  = (int*)(misc + 120 * 1024);
    int*   PERM = (int*)(misc + 124 * 1024);          // 32KB -> 156K
    u16*   WKVb = (u16*)(misc + 160 * 1024);          // [2,256,256] 256KB
    u16*   MCATb= (u16*)(misc + 416 * 1024);          // [768,256] 384KB
    u16*   WPh  = (u16*)(misc + 800 * 1024);          // [256,160] 80KB
    u16*   WPl  = (u16*)(misc + 880 * 1024);          // 80KB
    u16*   WHp  = (u16*)(misc + 960 * 1024);          // 1MB
    u16*   WLp  = (u16*)(misc + 1984 * 1024);         // 1MB

    const size_t OF1 = 0, OF2 = 131072, OAQ = 262144, OAO = 327680,
                 OW1 = 393216, OW2 = 458752;

    const dim3 gQ(NQ / 64, 4);
    const dim3 gT(TT * STOK / 64, 4);
    const dim3 gSEL(NQ / 64, 12);
    const dim3 gS(NQ / 4);

    // ---- input-only precomputation ----
    padsplit_kernel<<<160, blk, 0, stream>>>(tiw, WPh, WPl);
    wsplit_all<<<2048, blk, 0, stream>>>(f1w, f2w, aiw, aow, w1, w2, WHp, WLp);
    combine_kv32<<<512, blk, 0, stream>>>(aiw, aib, btw, btb, WKVb, bkv);
    mcat_kernel<<<dim3(16, 16, 3), blk, 0, stream>>>(tow, bpw, MCATb);
    uvs_kernel<<<3, blk, 0, stream>>>(tow, tob, bpw, bpb, Ubuf, Vbuf, Sbuf);
    feat32_kernel<<<NQ, blk, 0, stream>>>(xy, tq, c, st, Bm, tw, tbv, ce, FIN, IDX);

    // ---- bucket queries by time index (perm ordering) ----
    zcnt_kernel<<<2, blk, 0, stream>>>(CNT);
    hist_kernel<<<NQ / 256, blk, 0, stream>>>(IDX, CNT);
    scan_kernel<<<1, dim3(512), 0, stream>>>(CNT, BASE, CUR);
    scat_kernel<<<NQ / 256, blk, 0, stream>>>(IDX, CUR, PERM);

    // ---- K/V via MFMA bf16 (pre-converted weights), stored bf16 ----
    mgemm_b<1, 0><<<gT, blk, 0, stream>>>(hs, WKVb, bkv, nullptr, KA);
    mgemm_b<1, 0><<<gT, blk, 0, stream>>>(hs, WKVb + 65536, bkv + 256, nullptr, VA);

    // ---- trunk (split-precision MFMA, pre-split weights) ----
    mgemm3<0, 1, 0><<<gQ, blk, 0, stream>>>(FIN, 160, WPh, WPl, tib, nullptr,
                                            nullptr, nullptr, F, 160);
    for (int i = 0; i < 2; i++) {
        stats_kernel<<<gS, blk, 0, stream>>>(F, STT);
        mgemm3<1, 1, 0><<<gQ, blk, 0, stream>>>(F, 256, WHp + OF1 + (size_t)i * 65536,
                                                WLp + OF1 + (size_t)i * 65536,
                                                f1b + i * 256, STT, lng + i * 256,
                                                lnb + i * 256, H1, 256);
        mgemm3<0, 0, 1><<<gQ, blk, 0, stream>>>(H1, 256, WHp + OF2 + (size_t)i * 65536,
                                                WLp + OF2 + (size_t)i * 65536,
                                                f2b_ + i * 256, nullptr, nullptr,
                                                nullptr, F, 256);
    }
    // ---- q projection ----
    stats_kernel<<<gS, blk, 0, stream>>>(F, STT);
    mgemm3<1, 0, 0><<<gQ, blk, 0, stream>>>(F, 256, WHp + OAQ, WLp + OAQ, aib,
                                            STT, bng, bnb, Qb, 256);
    // ---- attention (vectorized, per-query blocks, perm-ordered) ----
    attn4_kernel<<<NQ, blk, 0, stream>>>(Qb, KA, VA, IDX, PERM);
    // ---- attn_out ----
    mgemm3<0, 0, 0><<<gQ, blk, 0, stream>>>(Qb, 256, WHp + OAO, WLp + OAO, aob,
                                            nullptr, nullptr, nullptr, C2, 256);
    // ---- bc correction block ----
    stats_kernel<<<gS, blk, 0, stream>>>(C2, STT);
    mgemm3<1, 1, 0><<<gQ, blk, 0, stream>>>(C2, 256, WHp + OW1, WLp + OW1, b1,
                                            STT, clg, clb, H1b, 256);
    mgemm3<0, 0, 1><<<gQ, blk, 0, stream>>>(H1b, 256, WHp + OW2, WLp + OW2, b2,
                                            nullptr, nullptr, nullptr, C2, 256);
    // ---- H[n] = M_{c[n]} @ C2[n] via MFMA SEL (pre-converted MCAT) ----
    mgemm_b<0, 1><<<gSEL, blk, 0, stream>>>(C2, MCATb, nullptr, c, H);
    // ---- final dot ----
    dot_kernel<<<NQ / 4, blk, 0, stream>>>(F, H, C2, c, Ubuf, Vbuf, Sbuf, lt, cs, cbv, out);
}

// Round 17
// 401.620 us; speedup vs baseline: 1.0959x; 1.0305x over previous
//
#include <hip/hip_runtime.h>
#include <cstdint>
#include <cstddef>

typedef unsigned short u16;
typedef __attribute__((ext_vector_type(8))) short s16x8;
typedef __attribute__((ext_vector_type(4))) float f32x4;

#define NQ   8192
#define TT   512
#define STOK 32

__device__ __forceinline__ float b2f(u16 u) {
    return __uint_as_float(((uint32_t)u) << 16);
}
__device__ __forceinline__ u16 f2b(float f) {
    uint32_t x = __float_as_uint(f);
    uint32_t r = (x + 0x7FFFu + ((x >> 16) & 1u)) >> 16;
    return (u16)r;
}
__device__ __forceinline__ float silu_f(float x) { return x / (1.f + expf(-x)); }

__global__ __launch_bounds__(256) void const_kernel(float v, float* __restrict__ out) {
    int i = blockIdx.x * 256 + threadIdx.x;
    if (i < NQ) out[i] = v;
}

// ---------------------------------------------------------------------------
// zero CNT[512] + STT pool [4][8192][2] floats (65536)
// ---------------------------------------------------------------------------
__global__ __launch_bounds__(256) void zero_kernel(int* __restrict__ cnt,
                                                   float* __restrict__ sttz) {
    int i = blockIdx.x * 256 + threadIdx.x;
    if (i < 512) cnt[i] = 0;
    int j = i - 512;
    if (j >= 0 && j < 65536) sttz[j] = 0.f;
}

// ---------------------------------------------------------------------------
// features (verified): FIN fp32 [NQ,160] (cols 152..159 = 0), IDX
// ---------------------------------------------------------------------------
__global__ __launch_bounds__(256) void feat32_kernel(
    const float* __restrict__ xy, const float* __restrict__ t_q,
    const int* __restrict__ c, const float* __restrict__ st,
    const float* __restrict__ B, const float* __restrict__ tw,
    const float* __restrict__ tb, const float* __restrict__ ce,
    float* __restrict__ FIN, int* __restrict__ IDX) {
    int n = blockIdx.x, t = threadIdx.x;
    float tq = t_q[n];
    int lo = 0, hi = TT;
    while (lo < hi) {
        int mid = (lo + hi) >> 1;
        if (st[mid] <= tq) lo = mid + 1; else hi = mid;
    }
    int idx = lo - 1;
    if (idx < 0) idx = 0;
    float dt = tq - st[idx];
    if (dt < 0.f) dt = 0.f;
    if (t == 0) IDX[n] = idx;
    float x = xy[2 * n], y = xy[2 * n + 1];
    size_t base = (size_t)n * 160;
    if (t < 64) { float p = x * B[t] + y * B[64 + t]; FIN[base + t] = cosf(p); }
    else if (t < 128) { int j = t - 64; float p = x * B[j] + y * B[64 + j]; FIN[base + t] = sinf(p); }
    else if (t < 144) { int j = t - 128; FIN[base + t] = dt * tw[j] + tb[j]; }
    else if (t < 152) { int j = t - 144; FIN[base + t] = ce[c[n] * 8 + j]; }
    else if (t < 160) { FIN[base + t] = 0.f; }
}

// ---------------------------------------------------------------------------
// split all trunk weights to bf16 hi/lo in one pass, incl. padded trunk_in_w.
// Pool layout (u16 idx): [0,131072) f1w | [..,262144) f2w | [..,327680) aiw_q
// | [..,393216) aow | [..,458752) w1 | [..,524288) w2 ; then trunk_in pad
// [524288, 565248) -> separate WPh/WPl buffers.
// ---------------------------------------------------------------------------
__global__ __launch_bounds__(256) void padwsplit_all(
    const float* __restrict__ f1w, const float* __restrict__ f2w,
    const float* __restrict__ aiw, const float* __restrict__ aow,
    const float* __restrict__ w1, const float* __restrict__ w2,
    const float* __restrict__ tiw,
    u16* __restrict__ WH, u16* __restrict__ WL,
    u16* __restrict__ WPh, u16* __restrict__ WPl) {
    int i = blockIdx.x * 256 + threadIdx.x;
    if (i >= 565248) return;
    if (i < 524288) {
        const float* src; int off;
        if (i < 131072)      { src = f1w; off = i; }
        else if (i < 262144) { src = f2w; off = i - 131072; }
        else if (i < 327680) { src = aiw; off = i - 262144; }
        else if (i < 393216) { src = aow; off = i - 327680; }
        else if (i < 458752) { src = w1;  off = i - 393216; }
        else                 { src = w2;  off = i - 458752; }
        float v = src[off];
        u16 h = f2b(v);
        WH[i] = h;
        WL[i] = f2b(v - b2f(h));
    } else {
        int j = i - 524288;            // 0..40959
        int r = j / 160, k = j % 160;
        float v = (k < 152) ? tiw[r * 152 + k] : 0.f;
        u16 h = f2b(v);
        WPh[j] = h;
        WPl[j] = f2b(v - b2f(h));
    }
}

// ---------------------------------------------------------------------------
// fold token projection into K/V weights; emit bf16 [512,256] + fp32 bias[512]
// ---------------------------------------------------------------------------
__global__ __launch_bounds__(256) void combine_kv32(
    const float* __restrict__ aiw, const float* __restrict__ aib,
    const float* __restrict__ btw, const float* __restrict__ btb,
    u16* __restrict__ WKVb, float* __restrict__ bkv) {
    int kv = blockIdx.x >> 8, m = blockIdx.x & 255;
    int d = threadIdx.x;
    __shared__ float wrow[256];
    wrow[d] = aiw[(size_t)(kv + 1) * 65536 + (size_t)m * 256 + d];
    __syncthreads();
    float acc = 0.f;
#pragma unroll 8
    for (int o = 0; o < 256; o++) acc += wrow[o] * btw[(size_t)o * 256 + d];
    WKVb[(size_t)kv * 65536 + (size_t)m * 256 + d] = f2b(acc);
    float pb = wrow[d] * btb[d];
#pragma unroll
    for (int mm = 32; mm >= 1; mm >>= 1) pb += __shfl_xor(pb, mm);
    __shared__ float red[4];
    if ((d & 63) == 0) red[d >> 6] = pb;
    __syncthreads();
    if (d == 0)
        bkv[kv * 256 + m] = red[0] + red[1] + red[2] + red[3] + aib[(kv + 1) * 256 + m];
}

// ---------------------------------------------------------------------------
// M_c = tow_c^T @ bpw_c (bilinear fold); emit bf16 directly
// ---------------------------------------------------------------------------
__global__ __launch_bounds__(256) void mcat_kernel(const float* __restrict__ tow,
                                                   const float* __restrict__ bpw,
                                                   u16* __restrict__ MCATb) {
    const int cc = blockIdx.z;
    const int t0 = blockIdx.x * 16, k0 = blockIdx.y * 16;
    const int lt = threadIdx.x & 15, lj = threadIdx.x >> 4;
    const int ot = threadIdx.x & 15, ok = threadIdx.x >> 4;
    __shared__ float As[16][17], Bs[16][17];
    float acc = 0.f;
    for (int j0 = 0; j0 < 256; j0 += 16) {
        As[lj][lt] = tow[((size_t)cc * 256 + j0 + lj) * 256 + t0 + lt];
        Bs[lj][lt] = bpw[((size_t)cc * 256 + j0 + lj) * 256 + k0 + lt];
        __syncthreads();
#pragma unroll
        for (int jj = 0; jj < 16; jj++) acc += As[jj][ot] * Bs[jj][ok];
        __syncthreads();
    }
    MCATb[((size_t)cc * 256 + t0 + ot) * 256 + k0 + ok] = f2b(acc);
}

__global__ __launch_bounds__(256) void uvs_kernel(
    const float* __restrict__ tow, const float* __restrict__ tob,
    const float* __restrict__ bpw, const float* __restrict__ bpb,
    float* __restrict__ U, float* __restrict__ V, float* __restrict__ S) {
    const int cc = blockIdx.x, t = threadIdx.x;
    float v = 0.f, u = 0.f;
    for (int r = 0; r < 256; r++) {
        v += tow[((size_t)cc * 256 + r) * 256 + t] * bpb[cc * 256 + r];
        u += bpw[((size_t)cc * 256 + r) * 256 + t] * tob[cc * 256 + r];
    }
    V[cc * 256 + t] = v;
    U[cc * 256 + t] = u;
    float sp = tob[cc * 256 + t] * bpb[cc * 256 + t];
#pragma unroll
    for (int m = 32; m >= 1; m >>= 1) sp += __shfl_xor(sp, m);
    __shared__ float red[4];
    if ((t & 63) == 0) red[t >> 6] = sp;
    __syncthreads();
    if (t == 0) S[cc] = red[0] + red[1] + red[2] + red[3];
}

// ---------------------------------------------------------------------------
// counting-sort of queries by IDX (512 buckets) -> perm
// ---------------------------------------------------------------------------
__global__ __launch_bounds__(256) void hist_kernel(const int* __restrict__ IDX,
                                                   int* __restrict__ cnt) {
    int n = blockIdx.x * 256 + threadIdx.x;
    if (n < NQ) atomicAdd(&cnt[IDX[n]], 1);
}
__global__ __launch_bounds__(512) void scan_kernel(const int* __restrict__ cnt,
                                                   int* __restrict__ base,
                                                   int* __restrict__ cur) {
    __shared__ int s[TT];
    int t = threadIdx.x;
    int v = cnt[t];
    s[t] = v;
    __syncthreads();
    for (int off = 1; off < TT; off <<= 1) {
        int add = (t >= off) ? s[t - off] : 0;
        __syncthreads();
        s[t] += add;
        __syncthreads();
    }
    base[t] = s[t] - v;
    cur[t] = s[t] - v;
}
__global__ __launch_bounds__(256) void scat_kernel(const int* __restrict__ IDX,
                                                   int* __restrict__ cur,
                                                   int* __restrict__ perm) {
    int n = blockIdx.x * 256 + threadIdx.x;
    if (n < NQ) {
        int pos = atomicAdd(&cur[IDX[n]], 1);
        perm[pos] = n;
    }
}

// ---------------------------------------------------------------------------
// mgemm_b: MFMA bf16 GEMM, A fp32 (converted on the fly), W pre-converted
// bf16. K=256, output stride ldc. ST16: store bf16. SEL: component select
// (N=768 grid, writes C[row*256+(col&255)]).
// ---------------------------------------------------------------------------
template <int ST16, int SEL>
__global__ __launch_bounds__(256) void mgemm_b(
    const float* __restrict__ A, const u16* __restrict__ Wb,
    const float* __restrict__ bias, const int* __restrict__ csel,
    void* __restrict__ Cv, int ldc) {
    __shared__ u16 As[64 * 40];
    __shared__ u16 Ws[64 * 40];
    const int t = threadIdx.x;
    const size_t rb = (size_t)blockIdx.x * 64;
    const size_t cb = (size_t)blockIdx.y * 64;
    const int wave = t >> 6, lane = t & 63;
    const int m16 = lane & 15, quad = lane >> 4;
    const int sr = t >> 2, sk = (t & 3) * 8;
    const float* Ap = A + (rb + sr) * 256 + sk;
    const u16* Wp = Wb + (cb + sr) * 256 + sk;

    f32x4 acc[4] = {};
    for (int k0 = 0; k0 < 256; k0 += 32) {
        float4 a0 = *(const float4*)(Ap + k0);
        float4 a1 = *(const float4*)(Ap + k0 + 4);
        u16 ta[8] = {f2b(a0.x), f2b(a0.y), f2b(a0.z), f2b(a0.w),
                     f2b(a1.x), f2b(a1.y), f2b(a1.z), f2b(a1.w)};
        *(uint4*)&As[sr * 40 + sk] = *(const uint4*)ta;
        *(uint4*)&Ws[sr * 40 + sk] = *(const uint4*)(Wp + k0);
        __syncthreads();
        s16x8 af = *(const s16x8*)&As[(wave * 16 + m16) * 40 + quad * 8];
#pragma unroll
        for (int ct = 0; ct < 4; ct++) {
            s16x8 bf = *(const s16x8*)&Ws[(ct * 16 + m16) * 40 + quad * 8];
            acc[ct] = __builtin_amdgcn_mfma_f32_16x16x32_bf16(af, bf, acc[ct], 0, 0, 0);
        }
        __syncthreads();
    }
#pragma unroll
    for (int ct = 0; ct < 4; ct++) {
        size_t col = cb + ct * 16 + m16;
        float bb = bias ? bias[col] : 0.f;
#pragma unroll
        for (int r = 0; r < 4; r++) {
            size_t row = rb + wave * 16 + quad * 4 + r;
            float x = acc[ct][r] + bb;
            if (SEL) {
                int comp = (int)(col >> 8);
                if (csel[row] == comp)
                    ((float*)Cv)[row * 256 + (col & 255)] = x;
            } else if (ST16) {
                ((u16*)Cv)[row * (size_t)ldc + col] = f2b(x);
            } else {
                ((float*)Cv)[row * (size_t)ldc + col] = x;
            }
        }
    }
}

// ---------------------------------------------------------------------------
// mgemm4: split-precision MFMA GEMM (3 MFMAs/step), A fp32 split on the fly,
// W pre-split hi/lo. LNA: LN A on load from raw (sum,sumsq) stats. ACT: silu.
// RES: C += old. STATS: epilogue accumulates per-row (sum,sumsq) into stOut
// via shfl-reduce + atomicAdd (stOut pre-zeroed).
// ---------------------------------------------------------------------------
template <int LNA, int ACT, int RES, int STATS>
__global__ __launch_bounds__(256) void mgemm4(
    const float* __restrict__ A, int lda, const u16* __restrict__ WH,
    const u16* __restrict__ WL, const float* __restrict__ bias,
    const float* __restrict__ stIn, const float* __restrict__ g,
    const float* __restrict__ bln, float* __restrict__ stOut,
    float* __restrict__ C, int K) {
    __shared__ u16 Ah[64 * 40], Al[64 * 40], Wh[64 * 40], Wl[64 * 40];
    const int t = threadIdx.x;
    const size_t rb = (size_t)blockIdx.x * 64;
    const size_t cb = (size_t)blockIdx.y * 64;
    const int wave = t >> 6, lane = t & 63;
    const int m16 = lane & 15, quad = lane >> 4;
    const int sr = t >> 2, sk = (t & 3) * 8;
    // LN params for the staged row (fixed across K-loop)
    float mean = 0.f, rstd = 0.f;
    if (LNA) {
        size_t ar = rb + sr;
        float s1 = stIn[2 * ar], s2 = stIn[2 * ar + 1];
        mean = s1 * (1.f / 256.f);
        float var = s2 * (1.f / 256.f) - mean * mean;
        rstd = rsqrtf(var + 1e-5f);
    }
    f32x4 acc[4] = {};
    for (int k0 = 0; k0 < K; k0 += 32) {
        {
            const float* p = A + (rb + sr) * (size_t)lda + k0 + sk;
            float4 v0 = *(const float4*)p;
            float4 v1 = *(const float4*)(p + 4);
            float va[8] = {v0.x, v0.y, v0.z, v0.w, v1.x, v1.y, v1.z, v1.w};
            if (LNA) {
#pragma unroll
                for (int e = 0; e < 8; e++)
                    va[e] = (va[e] - mean) * rstd * g[k0 + sk + e] + bln[k0 + sk + e];
            }
            u16 hi[8], lo[8];
#pragma unroll
            for (int e = 0; e < 8; e++) {
                hi[e] = f2b(va[e]);
                lo[e] = f2b(va[e] - b2f(hi[e]));
            }
            *(uint4*)&Ah[sr * 40 + sk] = *(const uint4*)hi;
            *(uint4*)&Al[sr * 40 + sk] = *(const uint4*)lo;
        }
        *(uint4*)&Wh[sr * 40 + sk] = *(const uint4*)(WH + (cb + sr) * (size_t)K + k0 + sk);
        *(uint4*)&Wl[sr * 40 + sk] = *(const uint4*)(WL + (cb + sr) * (size_t)K + k0 + sk);
        __syncthreads();
        s16x8 ah = *(const s16x8*)&Ah[(wave * 16 + m16) * 40 + quad * 8];
        s16x8 al = *(const s16x8*)&Al[(wave * 16 + m16) * 40 + quad * 8];
#pragma unroll
        for (int ct = 0; ct < 4; ct++) {
            s16x8 bh = *(const s16x8*)&Wh[(ct * 16 + m16) * 40 + quad * 8];
            s16x8 bl = *(const s16x8*)&Wl[(ct * 16 + m16) * 40 + quad * 8];
            acc[ct] = __builtin_amdgcn_mfma_f32_16x16x32_bf16(ah, bh, acc[ct], 0, 0, 0);
            acc[ct] = __builtin_amdgcn_mfma_f32_16x16x32_bf16(ah, bl, acc[ct], 0, 0, 0);
            acc[ct] = __builtin_amdgcn_mfma_f32_16x16x32_bf16(al, bh, acc[ct], 0, 0, 0);
        }
        __syncthreads();
    }
    float sr1[4] = {}, sr2[4] = {};
#pragma unroll
    for (int ct = 0; ct < 4; ct++) {
        size_t col = cb + ct * 16 + m16;
        float bb = bias ? bias[col] : 0.f;
#pragma unroll
        for (int r = 0; r < 4; r++) {
            size_t row = rb + wave * 16 + quad * 4 + r;
            float x = acc[ct][r] + bb;
            if (ACT) x = silu_f(x);
            if (RES) x += C[row * 256 + col];
            C[row * 256 + col] = x;
            if (STATS) { sr1[r] += x; sr2[r] += x * x; }
        }
    }
    if (STATS) {
#pragma unroll
        for (int r = 0; r < 4; r++) {
            float a = sr1[r], b = sr2[r];
#pragma unroll
            for (int m = 8; m >= 1; m >>= 1) {   // reduce over 16 m16 lanes
                a += __shfl_xor(a, m);
                b += __shfl_xor(b, m);
            }
            if (m16 == 0) {
                size_t row = rb + wave * 16 + quad * 4 + r;
                atomicAdd(&stOut[2 * row], a);
                atomicAdd(&stOut[2 * row + 1], b);
            }
        }
    }
}

// ---------------------------------------------------------------------------
// attn4: one block per query (perm-ordered). KV interleaved [16384,512] bf16:
// K at row*512, V at row*512+256. Vectorized loads, shfl softmax.
// In-place Qb -> CTX.
// ---------------------------------------------------------------------------
__global__ __launch_bounds__(256) void attn4_kernel(
    float* __restrict__ QC, const u16* __restrict__ KV,
    const int* __restrict__ idx, const int* __restrict__ perm) {
    __shared__ u16 vsh[STOK * 264];
    __shared__ float qsh[256], attw[4][STOK];
    const int n = perm[blockIdx.x];
    const int t = threadIdx.x;
    qsh[t] = QC[(size_t)n * 256 + t];
    int ii = idx[n];
    ii = ii < 0 ? 0 : (ii > TT - 1 ? TT - 1 : ii);
    const u16* kvb = KV + (size_t)ii * STOK * 512;
#pragma unroll
    for (int i = t; i < 1024; i += 256) {
        int s = i >> 5, dq = (i & 31) * 8;
        *(uint4*)&vsh[s * 264 + dq] = *(const uint4*)&kvb[(size_t)s * 512 + 256 + dq];
    }
    __syncthreads();
    if (t < 128) {
        int h = t >> 5, s = t & 31;
        const u16* kp = kvb + (size_t)s * 512 + h * 64;
        uint4 kv[8];
#pragma unroll
        for (int dq = 0; dq < 8; dq++) kv[dq] = *(const uint4*)(kp + dq * 8);
        float p0 = 0.f, p1 = 0.f;
#pragma unroll
        for (int dq = 0; dq < 8; dq++) {
            const u16* ks = (const u16*)&kv[dq];
            float a0 = 0.f;
#pragma unroll
            for (int j = 0; j < 8; j++) a0 += qsh[h * 64 + dq * 8 + j] * b2f(ks[j]);
            if (dq & 1) p1 += a0; else p0 += a0;
        }
        float sc = (p0 + p1) * 0.125f;
        float mx = sc;
#pragma unroll
        for (int m = 16; m >= 1; m >>= 1) mx = fmaxf(mx, __shfl_xor(mx, m));
        float e = expf(sc - mx);
        float sum = e;
#pragma unroll
        for (int m = 16; m >= 1; m >>= 1) sum += __shfl_xor(sum, m);
        attw[h][s] = e / sum;
    }
    __syncthreads();
    {
        int h = t >> 6;
        float a = 0.f;
#pragma unroll 8
        for (int s = 0; s < STOK; s++) a += attw[h][s] * b2f(vsh[s * 264 + t]);
        QC[(size_t)n * 256 + t] = a;
    }
}

// ---------------------------------------------------------------------------
// final dot: out[n] = (F·H + F·v_cc + u_cc·C2 + s_cc) * exp(lt)*cs + cb
// ---------------------------------------------------------------------------
__global__ __launch_bounds__(256) void dot_kernel(
    const float* __restrict__ F, const float* __restrict__ H,
    const float* __restrict__ C2, const int* __restrict__ c,
    const float* __restrict__ U, const float* __restrict__ V,
    const float* __restrict__ S, const float* __restrict__ lt,
    const float* __restrict__ cs, const float* __restrict__ cbv,
    float* __restrict__ out) {
    const int n = blockIdx.x * 4 + (threadIdx.x >> 6);
    const int lane = threadIdx.x & 63;
    const int cc = c[n];
    float4 f4 = *(const float4*)&F[(size_t)n * 256 + lane * 4];
    float4 h4 = *(const float4*)&H[(size_t)n * 256 + lane * 4];
    float4 g4 = *(const float4*)&C2[(size_t)n * 256 + lane * 4];
    float4 v4 = *(const float4*)&V[cc * 256 + lane * 4];
    float4 u4 = *(const float4*)&U[cc * 256 + lane * 4];
    float a = f4.x * (h4.x + v4.x) + f4.y * (h4.y + v4.y) +
              f4.z * (h4.z + v4.z) + f4.w * (h4.w + v4.w) +
              u4.x * g4.x + u4.y * g4.y + u4.z * g4.z + u4.w * g4.w;
#pragma unroll
    for (int m = 32; m >= 1; m >>= 1) a += __shfl_xor(a, m);
    if (lane == 0)
        out[n] = (a + S[cc]) * expf(lt[0]) * cs[cc] + cbv[cc];
}

// ---------------------------------------------------------------------------
extern "C" void kernel_launch(void* const* d_in, const int* in_sizes, int n_in,
                              void* d_out, int out_size, void* d_ws, size_t ws_size,
                              hipStream_t stream) {
    float* out = (float*)d_out;
    const dim3 blk(256);

    static const int EXPECT[38] = {
        16384, 8192, 8192, 4194304, 512, 128, 16, 16, 24,
        38912, 256, 512, 512, 131072, 512, 131072, 512,
        65536, 256, 256, 256, 196608, 768, 65536, 256,
        256, 256, 65536, 256, 65536, 256, 196608, 768,
        196608, 768, 1, 3, 3};
    if (n_in != 38) { const_kernel<<<NQ / 256, blk, 0, stream>>>(99.0e6f, out); return; }
    for (int i = 0; i < 38; i++)
        if (in_sizes[i] != EXPECT[i]) {
            const_kernel<<<NQ / 256, blk, 0, stream>>>((100.0f + i) * 1.0e6f, out);
            return;
        }

    const float* xy  = (const float*)d_in[0];
    const float* tq  = (const float*)d_in[1];
    const int*   c   = (const int*)d_in[2];
    const float* hs  = (const float*)d_in[3];
    const float* st  = (const float*)d_in[4];
    const float* Bm  = (const float*)d_in[5];
    const float* tw  = (const float*)d_in[6];
    const float* tbv = (const float*)d_in[7];
    const float* ce  = (const float*)d_in[8];
    const float* tiw = (const float*)d_in[9];
    const float* tib = (const float*)d_in[10];
    const float* lng = (const float*)d_in[11];
    const float* lnb = (const float*)d_in[12];
    const float* f1w = (const float*)d_in[13];
    const float* f1b = (const float*)d_in[14];
    const float* f2w = (const float*)d_in[15];
    const float* f2b_ = (const float*)d_in[16];
    const float* btw = (const float*)d_in[17];
    const float* btb = (const float*)d_in[18];
    const float* bng = (const float*)d_in[19];
    const float* bnb = (const float*)d_in[20];
    const float* aiw = (const float*)d_in[21];
    const float* aib = (const float*)d_in[22];
    const float* aow = (const float*)d_in[23];
    const float* aob = (const float*)d_in[24];
    const float* clg = (const float*)d_in[25];
    const float* clb = (const float*)d_in[26];
    const float* w1  = (const float*)d_in[27];
    const float* b1  = (const float*)d_in[28];
    const float* w2  = (const float*)d_in[29];
    const float* b2  = (const float*)d_in[30];
    const float* tow = (const float*)d_in[31];
    const float* tob = (const float*)d_in[32];
    const float* bpw = (const float*)d_in[33];
    const float* bpb = (const float*)d_in[34];
    const float* lt  = (const float*)d_in[35];
    const float* cs  = (const float*)d_in[36];
    const float* cbv = (const float*)d_in[37];

    char* ws = (char*)d_ws;
    const size_t MB = 1 << 20;
    if (ws_size < 44 * MB) {
        const_kernel<<<NQ / 256, blk, 0, stream>>>(8.0e6f, out);
        return;
    }

    // KV interleaved [16384,512] bf16 = 16 MB at [0,16). Slots 8 MB each.
    u16*   KV   = (u16*)(ws + 0 * MB);
    char*  S_A  = ws + 16 * MB;   // FIN -> Qb/CTX -> H1b -> H
    char*  S_B  = ws + 24 * MB;   // F (persists)
    char*  S_C  = ws + 32 * MB;   // H1 -> C2
    char*  misc = ws + 40 * MB;
    float* FIN  = (float*)S_A;
    float* Qb   = (float*)S_A;
    float* H1b  = (float*)S_A;
    float* H    = (float*)S_A;
    float* F    = (float*)S_B;
    float* H1   = (float*)S_C;
    float* C2   = (float*)S_C;
    int*   IDX  = (int*)(misc + 0);                   // 32KB
    float* bkv  = (float*)(misc + 32 * 1024);         // 4KB
    float* Ubuf = (float*)(misc + 36 * 1024);
    float* Vbuf = (float*)(misc + 40 * 1024);
    float* Sbuf = (float*)(misc + 44 * 1024);
    int*   CNT  = (int*)(misc + 48 * 1024);
    int*   BASE = (int*)(misc + 52 * 1024);
    int*   CUR  = (int*)(misc + 56 * 1024);
    int*   PERM = (int*)(misc + 60 * 1024);           // 32KB -> 92K
    float* STTZ = (float*)(misc + 92 * 1024);         // 4x[8192,2] = 256KB -> 348K
    u16*   WKVb = (u16*)(misc + 348 * 1024);          // [512,256] 256KB -> 604K
    u16*   MCATb= (u16*)(misc + 604 * 1024);          // [768,256] 384KB -> 988K
    u16*   WPh  = (u16*)(misc + 988 * 1024);          // 80KB
    u16*   WPl  = (u16*)(misc + 1068 * 1024);         // 80KB
    u16*   WHp  = (u16*)(misc + 1148 * 1024);         // 1MB
    u16*   WLp  = (u16*)(misc + 2172 * 1024);         // 1MB -> ~3.1MB

    float* ST0 = STTZ + 0;       // after trunk_in
    float* ST1 = STTZ + 16384;   // after fc2(0)
    float* ST2 = STTZ + 32768;   // after fc2(1)
    float* ST3 = STTZ + 49152;   // after attn_out

    const size_t OF1 = 0, OF2 = 131072, OAQ = 262144, OAO = 327680,
                 OW1 = 393216, OW2 = 458752;

    const dim3 gQ(NQ / 64, 4);
    const dim3 gKV(TT * STOK / 64, 8);   // M=16384, N=512
    const dim3 gSEL(NQ / 64, 12);

    // ---- prep (input-only) ----
    zero_kernel<<<258, blk, 0, stream>>>(CNT, STTZ);
    padwsplit_all<<<2208, blk, 0, stream>>>(f1w, f2w, aiw, aow, w1, w2, tiw,
                                            WHp, WLp, WPh, WPl);
    combine_kv32<<<512, blk, 0, stream>>>(aiw, aib, btw, btb, WKVb, bkv);
    mcat_kernel<<<dim3(16, 16, 3), blk, 0, stream>>>(tow, bpw, MCATb);
    uvs_kernel<<<3, blk, 0, stream>>>(tow, tob, bpw, bpb, Ubuf, Vbuf, Sbuf);
    feat32_kernel<<<NQ, blk, 0, stream>>>(xy, tq, c, st, Bm, tw, tbv, ce, FIN, IDX);

    // ---- sort queries by time index ----
    hist_kernel<<<NQ / 256, blk, 0, stream>>>(IDX, CNT);
    scan_kernel<<<1, dim3(512), 0, stream>>>(CNT, BASE, CUR);
    scat_kernel<<<NQ / 256, blk, 0, stream>>>(IDX, CUR, PERM);

    // ---- K/V (single merged GEMM, bf16 interleaved output) ----
    mgemm_b<1, 0><<<gKV, blk, 0, stream>>>(hs, WKVb, bkv, nullptr, KV, 512);

    // ---- trunk (stats fused into epilogues) ----
    mgemm4<0, 1, 0, 1><<<gQ, blk, 0, stream>>>(FIN, 160, WPh, WPl, tib,
                                               nullptr, nullptr, nullptr, ST0, F, 160);
    mgemm4<1, 1, 0, 0><<<gQ, blk, 0, stream>>>(F, 256, WHp + OF1, WLp + OF1, f1b,
                                               ST0, lng, lnb, nullptr, H1, 256);
    mgemm4<0, 0, 1, 1><<<gQ, blk, 0, stream>>>(H1, 256, WHp + OF2, WLp + OF2, f2b_,
                                               nullptr, nullptr, nullptr, ST1, F, 256);
    mgemm4<1, 1, 0, 0><<<gQ, blk, 0, stream>>>(F, 256, WHp + OF1 + 65536,
                                               WLp + OF1 + 65536, f1b + 256,
                                               ST1, lng + 256, lnb + 256, nullptr, H1, 256);
    mgemm4<0, 0, 1, 1><<<gQ, blk, 0, stream>>>(H1, 256, WHp + OF2 + 65536,
                                               WLp + OF2 + 65536, f2b_ + 256,
                                               nullptr, nullptr, nullptr, ST2, F, 256);
    // ---- q projection ----
    mgemm4<1, 0, 0, 0><<<gQ, blk, 0, stream>>>(F, 256, WHp + OAQ, WLp + OAQ, aib,
                                               ST2, bng, bnb, nullptr, Qb, 256);
    // ---- attention ----
    attn4_kernel<<<NQ, blk, 0, stream>>>(Qb, KV, IDX, PERM);
    // ---- attn_out (stats -> ST3) ----
    mgemm4<0, 0, 0, 1><<<gQ, blk, 0, stream>>>(Qb, 256, WHp + OAO, WLp + OAO, aob,
                                               nullptr, nullptr, nullptr, ST3, C2, 256);
    // ---- bc correction block ----
    mgemm4<1, 1, 0, 0><<<gQ, blk, 0, stream>>>(C2, 256, WHp + OW1, WLp + OW1, b1,
                                               ST3, clg, clb, nullptr, H1b, 256);
    mgemm4<0, 0, 1, 0><<<gQ, blk, 0, stream>>>(H1b, 256, WHp + OW2, WLp + OW2, b2,
                                               nullptr, nullptr, nullptr, nullptr, C2, 256);
    // ---- H[n] = M_{c[n]} @ C2[n] (SEL) ----
    mgemm_b<0, 1><<<gSEL, blk, 0, stream>>>(C2, MCATb, nullptr, c, H, 256);
    // ---- final dot ----
    dot_kernel<<<NQ / 4, blk, 0, stream>>>(F, H, C2, c, Ubuf, Vbuf, Sbuf, lt, cs, cbv, out);
}